// Round 1
// baseline (19877.986 us; speedup 1.0000x reference)
//
#include <hip/hip_runtime.h>
#include <hip/hip_bf16.h>

// Problem constants
#define NB 32      // batch
#define TD 128     // decode steps
#define SE 256     // encoder length
#define HD 512     // hidden
#define EEnc 512   // encoder dim
#define EMB 256    // embedding dim
#define NV 32000   // vocab

typedef __attribute__((ext_vector_type(8))) short bf16x8;
typedef __attribute__((ext_vector_type(4))) float f32x4;

__device__ __forceinline__ float fsigm(float x){ return 1.f/(1.f+__expf(-x)); }
__device__ __forceinline__ float ftanh(float x){
  float c = fminf(fmaxf(x,-15.f),15.f);
  float e = __expf(2.f*c);
  return (e-1.f)/(e+1.f);
}

// ---------------- prologue kernels ----------------

__global__ __launch_bounds__(256) void k_init(float* z){
  z[(size_t)blockIdx.x*256 + threadIdx.x] = 0.f;
}

__global__ __launch_bounds__(256) void k_gather(const float* __restrict__ emb, const int* __restrict__ tok,
                                                float* __restrict__ emb_g){
  int row = blockIdx.x;                       // b*TD + t
  int tk = tok[row];
  emb_g[(size_t)row*EMB + threadIdx.x] = emb[(size_t)tk*EMB + threadIdx.x];
}

// key_proj = enc @ Wk^T + bk : M=8192 (b,s), N=512 (h), K=512. fp32 classic tile GEMM.
// 128x128 tile, 8x8 per thread. One-time (~40us), fp32 kept for recurrence accuracy.
__global__ __launch_bounds__(256) void k_keyproj(const float* __restrict__ enc, const float* __restrict__ Wk,
                                                 const float* __restrict__ bk, float* __restrict__ kp){
  __shared__ float As[16][136];     // [kk][row], padded
  __shared__ float Bs[16*164];      // [tx][kk][8] with stride 164 floats per tx (bank-friendly)
  int tid = threadIdx.x;
  int bn = blockIdx.x, bm = blockIdx.y;
  int tx = tid & 15, ty = tid >> 4;
  float acc[8][8];
  #pragma unroll
  for (int i=0;i<8;i++)
    #pragma unroll
    for (int j=0;j<8;j++) acc[i][j]=0.f;
  for (int k0=0;k0<512;k0+=16){
    __syncthreads();
    #pragma unroll
    for (int r=0;r<8;r++){
      int idx = tid + r*256;
      int row = idx >> 4, kk = idx & 15;
      As[kk][row] = enc[(size_t)(bm*128+row)*EEnc + k0 + kk];
      float wv = Wk[(size_t)(bn*128+row)*EEnc + k0 + kk];
      Bs[(row>>3)*164 + kk*8 + (row&7)] = wv;
    }
    __syncthreads();
    #pragma unroll 4
    for (int kk=0;kk<16;kk++){
      float a[8], b[8];
      *(float4*)(a)   = *(float4*)&As[kk][ty*8];
      *(float4*)(a+4) = *(float4*)&As[kk][ty*8+4];
      *(float4*)(b)   = *(float4*)&Bs[tx*164 + kk*8];
      *(float4*)(b+4) = *(float4*)&Bs[tx*164 + kk*8 + 4];
      #pragma unroll
      for (int i=0;i<8;i++)
        #pragma unroll
        for (int j=0;j<8;j++) acc[i][j] += a[i]*b[j];
    }
  }
  #pragma unroll
  for (int i=0;i<8;i++){
    int row = bm*128 + ty*8 + i;
    #pragma unroll
    for (int j=0;j<8;j++){
      int col = bn*128 + tx*8 + j;
      kp[(size_t)row*HD + col] = acc[i][j] + bk[col];
    }
  }
}

// Wcat0[j][0:768]=Wih0[j], [768:1280]=Whh0[j]; bcat = bih+bhh
__global__ __launch_bounds__(256) void k_wcat0(const float* __restrict__ Wih, const float* __restrict__ Whh,
                                               const float* __restrict__ bih, const float* __restrict__ bhh,
                                               float* __restrict__ Wcat, float* __restrict__ bcat){
  int j = blockIdx.x;
  for (int k=threadIdx.x;k<1280;k+=256){
    float v = (k<768) ? Wih[(size_t)j*768+k] : Whh[(size_t)j*512 + (k-768)];
    Wcat[(size_t)j*1280+k] = v;
  }
  if (threadIdx.x==0) bcat[j] = bih[j]+bhh[j];
}
__global__ __launch_bounds__(256) void k_wcat1(const float* __restrict__ Wih, const float* __restrict__ Whh,
                                               const float* __restrict__ bih, const float* __restrict__ bhh,
                                               float* __restrict__ Wcat, float* __restrict__ bcat){
  int j = blockIdx.x;
  for (int k=threadIdx.x;k<1024;k+=256){
    float v = (k<512) ? Wih[(size_t)j*512+k] : Whh[(size_t)j*512 + (k-512)];
    Wcat[(size_t)j*1024+k] = v;
  }
  if (threadIdx.x==0) bcat[j] = bih[j]+bhh[j];
}

// Wout fp32 -> bf16 (one row per block)
__global__ __launch_bounds__(256) void k_cvtw(const float* __restrict__ W, unsigned short* __restrict__ Wb){
  size_t base = (size_t)blockIdx.x*1024 + threadIdx.x*4;
  float4 v = *(const float4*)(W + base);
  __hip_bfloat16 b0 = __float2bfloat16(v.x), b1 = __float2bfloat16(v.y);
  __hip_bfloat16 b2 = __float2bfloat16(v.z), b3 = __float2bfloat16(v.w);
  ushort4 o;
  o.x = *(unsigned short*)&b0; o.y = *(unsigned short*)&b1;
  o.z = *(unsigned short*)&b2; o.w = *(unsigned short*)&b3;
  *(ushort4*)(Wb + base) = o;
}

// ---------------- per-step kernels ----------------

// Head: activate h1_{t-1} from part1 (gates of step t-1) + c1 ping-pong; write h1buf, X row t-1.
// Body: qw[b][h] = bq[h] + sum_e h1[b][e]*Wq[h][e].  grid (2 h-chunks, 8 b-groups of 4).
__global__ __launch_bounds__(256) void k_qw(const float* __restrict__ part1, const float* __restrict__ bcat1,
                                            const float* __restrict__ c1in, float* __restrict__ c1out,
                                            const float* __restrict__ Wq, const float* __restrict__ bq,
                                            float* __restrict__ qw, float* __restrict__ h1buf,
                                            __hip_bfloat16* __restrict__ X, int t){
  int hc = blockIdx.x, bg = blockIdx.y;
  int tid = threadIdx.x;
  // h1 activation for b in [bg*4, bg*4+4), all e (duplicated across hc blocks; identical values)
  for (int idx=tid; idx<2048; idx+=256){
    int bl = idx >> 9;
    int e  = idx & 511;
    int b  = bg*4 + bl;
    float gi = bcat1[e], gf = bcat1[512+e], gg = bcat1[1024+e], go = bcat1[1536+e];
    #pragma unroll
    for (int k2=0;k2<8;k2++){
      const float* p = part1 + (size_t)k2*65536 + (size_t)b*2048;
      gi += p[e]; gf += p[512+e]; gg += p[1024+e]; go += p[1536+e];
    }
    float cp = c1in[b*512+e];
    float cn = fsigm(gf)*cp + fsigm(gi)*ftanh(gg);
    float hn = fsigm(go)*ftanh(cn);
    c1out[b*512+e] = cn;
    h1buf[b*512+e] = hn;
    if (t > 0) X[((size_t)(b*TD + (t-1)))*1024 + e] = __float2bfloat16(hn);
  }
  __syncthreads();   // h1buf writes visible to this block (same CU; barrier drains vmem)
  int h = hc*256 + tid;
  const float* wr = Wq + (size_t)h*HD;
  const float* x0 = h1buf + (size_t)(bg*4+0)*HD;
  const float* x1 = h1buf + (size_t)(bg*4+1)*HD;
  const float* x2 = h1buf + (size_t)(bg*4+2)*HD;
  const float* x3 = h1buf + (size_t)(bg*4+3)*HD;
  float bqh = bq[h];
  float a0=bqh, a1=bqh, a2=bqh, a3=bqh;
  #pragma unroll 4
  for (int e=0;e<HD;e+=4){
    float4 w4 = *(const float4*)(wr+e);
    float4 v0 = *(const float4*)(x0+e);
    float4 v1 = *(const float4*)(x1+e);
    float4 v2 = *(const float4*)(x2+e);
    float4 v3 = *(const float4*)(x3+e);
    a0 += w4.x*v0.x + w4.y*v0.y + w4.z*v0.z + w4.w*v0.w;
    a1 += w4.x*v1.x + w4.y*v1.y + w4.z*v1.z + w4.w*v1.w;
    a2 += w4.x*v2.x + w4.y*v2.y + w4.z*v2.z + w4.w*v2.w;
    a3 += w4.x*v3.x + w4.y*v3.y + w4.z*v3.z + w4.w*v3.w;
  }
  qw[(size_t)(bg*4+0)*HD + h] = a0;
  qw[(size_t)(bg*4+1)*HD + h] = a1;
  qw[(size_t)(bg*4+2)*HD + h] = a2;
  qw[(size_t)(bg*4+3)*HD + h] = a3;
}

// scores[b][s] = sum_h tanh(kp[b][s][h] + qw[b][h]) * v[h].  grid (8 s-chunks, 32 b).
__global__ __launch_bounds__(256) void k_scores(const float* __restrict__ kp, const float* __restrict__ qw,
                                                const float* __restrict__ vv, float* __restrict__ scores){
  int sc = blockIdx.x, b = blockIdx.y;
  __shared__ float qwl[512], vl[512];
  int tid = threadIdx.x;
  qwl[tid]     = qw[(size_t)b*HD + tid];
  qwl[tid+256] = qw[(size_t)b*HD + tid + 256];
  vl[tid]      = vv[tid];
  vl[tid+256]  = vv[tid+256];
  __syncthreads();
  int wave = tid>>6, lane = tid&63;
  for (int si=0; si<8; si++){
    int s = sc*32 + wave*8 + si;
    const float* row = kp + ((size_t)b*SE + s)*HD;
    float acc = 0.f;
    #pragma unroll
    for (int h=lane; h<HD; h+=64) acc += ftanh(row[h]+qwl[h]) * vl[h];
    for (int o=32;o;o>>=1) acc += __shfl_down(acc,o);
    if (lane==0) scores[b*SE+s] = acc;
  }
}

// softmax over s + ctx[b][e] = sum_s w[s]*enc[b][s][e].  grid (2 e-chunks, 32 b).
__global__ __launch_bounds__(256) void k_ctx(const float* __restrict__ scores, const float* __restrict__ enc,
                                             float* __restrict__ ctx, __hip_bfloat16* __restrict__ X, int t){
  int ec = blockIdx.x, b = blockIdx.y;
  __shared__ float w[256];
  __shared__ float red[16];
  int tid = threadIdx.x, lane = tid&63, wv = tid>>6;
  float sv = scores[b*SE + tid];
  float m = sv;
  for (int o=32;o;o>>=1) m = fmaxf(m, __shfl_down(m,o));
  if (lane==0) red[wv] = m;
  __syncthreads();
  m = fmaxf(fmaxf(red[0],red[1]),fmaxf(red[2],red[3]));
  float e = __expf(sv - m);
  w[tid] = e;
  float s = e;
  for (int o=32;o;o>>=1) s += __shfl_down(s,o);
  if (lane==0) red[4+wv] = s;
  __syncthreads();
  float inv = 1.f/(red[4]+red[5]+red[6]+red[7]);
  int e0 = ec*256 + tid;
  const float* ep = enc + (size_t)b*SE*EEnc + e0;
  float acc = 0.f;
  #pragma unroll 2
  for (int s4=0;s4<SE;s4+=4){
    float4 w4 = *(float4*)&w[s4];
    acc += w4.x*ep[(size_t)(s4  )*EEnc];
    acc += w4.y*ep[(size_t)(s4+1)*EEnc];
    acc += w4.z*ep[(size_t)(s4+2)*EEnc];
    acc += w4.w*ep[(size_t)(s4+3)*EEnc];
  }
  acc *= inv;
  ctx[(size_t)b*HD + e0] = acc;
  X[((size_t)(b*TD + t))*1024 + 512 + e0] = __float2bfloat16(acc);
}

// gates0 partial GEMM: part0[ks][b][j] = sum_{k in slice} Wcat0[j][k]*x0[b][k]
// x0 = [emb_t(256) | ctx(512) | h0_{t-1}(512)].  grid (8 k-slices of 160, 8 b-groups of 4).
__global__ __launch_bounds__(256) void k_g0(const float* __restrict__ Wcat0, const float* __restrict__ emb_g,
                                            const float* __restrict__ ctx, const float* __restrict__ h0buf,
                                            float* __restrict__ part0, int t){
  int ks = blockIdx.x, bg = blockIdx.y;
  int tid = threadIdx.x;
  __shared__ float xl[4][160];
  for (int idx=tid; idx<640; idx+=256){
    int bl = idx/160; int kk = idx - bl*160;
    int k = ks*160 + kk;
    int b = bg*4 + bl;
    float v;
    if (k < 256)      v = emb_g[((size_t)(b*TD + t))*EMB + k];
    else if (k < 768) v = ctx[(size_t)b*HD + (k-256)];
    else              v = h0buf[(size_t)b*HD + (k-768)];
    xl[bl][kk] = v;
  }
  __syncthreads();
  const float* wp[8];
  #pragma unroll
  for (int jj=0;jj<8;jj++) wp[jj] = Wcat0 + (size_t)(jj*256+tid)*1280 + ks*160;
  float acc[8][4];
  #pragma unroll
  for (int jj=0;jj<8;jj++){ acc[jj][0]=0.f; acc[jj][1]=0.f; acc[jj][2]=0.f; acc[jj][3]=0.f; }
  #pragma unroll 2
  for (int k=0;k<160;k+=4){
    float4 x0 = *(float4*)&xl[0][k];
    float4 x1 = *(float4*)&xl[1][k];
    float4 x2 = *(float4*)&xl[2][k];
    float4 x3 = *(float4*)&xl[3][k];
    #pragma unroll
    for (int jj=0;jj<8;jj++){
      float4 w4 = *(const float4*)(wp[jj]+k);
      acc[jj][0] += w4.x*x0.x + w4.y*x0.y + w4.z*x0.z + w4.w*x0.w;
      acc[jj][1] += w4.x*x1.x + w4.y*x1.y + w4.z*x1.z + w4.w*x1.w;
      acc[jj][2] += w4.x*x2.x + w4.y*x2.y + w4.z*x2.z + w4.w*x2.w;
      acc[jj][3] += w4.x*x3.x + w4.y*x3.y + w4.z*x3.z + w4.w*x3.w;
    }
  }
  float* pb = part0 + (size_t)ks*65536 + (size_t)(bg*4)*2048;
  #pragma unroll
  for (int jj=0;jj<8;jj++)
    #pragma unroll
    for (int bl=0;bl<4;bl++)
      pb[(size_t)bl*2048 + jj*256 + tid] = acc[jj][bl];
}

// gates1 partial GEMM with fused h0 activation at head (k-slices 0..3 own h0/c0 updates).
// x = [h0_t(512) | h1_{t-1}(512)].  grid (8 k-slices of 128, 8 b-groups of 4).
__global__ __launch_bounds__(256) void k_g1(const float* __restrict__ Wcat1, const float* __restrict__ part0,
                                            const float* __restrict__ bcat0, float* __restrict__ c0,
                                            float* __restrict__ h0buf, const float* __restrict__ h1buf,
                                            float* __restrict__ part1){
  int ks = blockIdx.x, bg = blockIdx.y;
  int tid = threadIdx.x;
  __shared__ float xl[4][128];
  if (ks < 4){
    for (int idx=tid; idx<512; idx+=256){
      int bl = idx>>7, ul = idx&127;
      int b = bg*4+bl, u = ks*128+ul;
      float gi = bcat0[u], gf = bcat0[512+u], gg = bcat0[1024+u], go = bcat0[1536+u];
      #pragma unroll
      for (int k2=0;k2<8;k2++){
        const float* p = part0 + (size_t)k2*65536 + (size_t)b*2048;
        gi += p[u]; gf += p[512+u]; gg += p[1024+u]; go += p[1536+u];
      }
      float cp = c0[(size_t)b*HD + u];
      float cn = fsigm(gf)*cp + fsigm(gi)*ftanh(gg);
      float hn = fsigm(go)*ftanh(cn);
      c0[(size_t)b*HD + u] = cn;
      h0buf[(size_t)b*HD + u] = hn;
      xl[bl][ul] = hn;
    }
  } else {
    for (int idx=tid; idx<512; idx+=256){
      int bl = idx>>7, ul = idx&127;
      xl[bl][ul] = h1buf[(size_t)(bg*4+bl)*HD + (ks-4)*128 + ul];
    }
  }
  __syncthreads();
  const float* wp[8];
  #pragma unroll
  for (int jj=0;jj<8;jj++) wp[jj] = Wcat1 + (size_t)(jj*256+tid)*1024 + ks*128;
  float acc[8][4];
  #pragma unroll
  for (int jj=0;jj<8;jj++){ acc[jj][0]=0.f; acc[jj][1]=0.f; acc[jj][2]=0.f; acc[jj][3]=0.f; }
  #pragma unroll 2
  for (int k=0;k<128;k+=4){
    float4 x0 = *(float4*)&xl[0][k];
    float4 x1 = *(float4*)&xl[1][k];
    float4 x2 = *(float4*)&xl[2][k];
    float4 x3 = *(float4*)&xl[3][k];
    #pragma unroll
    for (int jj=0;jj<8;jj++){
      float4 w4 = *(const float4*)(wp[jj]+k);
      acc[jj][0] += w4.x*x0.x + w4.y*x0.y + w4.z*x0.z + w4.w*x0.w;
      acc[jj][1] += w4.x*x1.x + w4.y*x1.y + w4.z*x1.z + w4.w*x1.w;
      acc[jj][2] += w4.x*x2.x + w4.y*x2.y + w4.z*x2.z + w4.w*x2.w;
      acc[jj][3] += w4.x*x3.x + w4.y*x3.y + w4.z*x3.z + w4.w*x3.w;
    }
  }
  float* pb = part1 + (size_t)ks*65536 + (size_t)(bg*4)*2048;
  #pragma unroll
  for (int jj=0;jj<8;jj++)
    #pragma unroll
    for (int bl=0;bl<4;bl++)
      pb[(size_t)bl*2048 + jj*256 + tid] = acc[jj][bl];
}

// Final: activate h1_127, write X row 127 and the h,c output sections.
__global__ __launch_bounds__(256) void k_fin(const float* __restrict__ part1, const float* __restrict__ bcat1,
                                             const float* __restrict__ c1in, const float* __restrict__ h0buf,
                                             const float* __restrict__ c0, __hip_bfloat16* __restrict__ X,
                                             float* __restrict__ out){
  const size_t OUT_H = (size_t)NB*TD*NV;
  const size_t OUT_C = OUT_H + 2*NB*HD;
  int idx = blockIdx.x*256 + threadIdx.x;     // 0..16383
  int b = idx >> 9, e = idx & 511;
  float gi = bcat1[e], gf = bcat1[512+e], gg = bcat1[1024+e], go = bcat1[1536+e];
  #pragma unroll
  for (int k2=0;k2<8;k2++){
    const float* p = part1 + (size_t)k2*65536 + (size_t)b*2048;
    gi += p[e]; gf += p[512+e]; gg += p[1024+e]; go += p[1536+e];
  }
  float cp = c1in[idx];
  float cn = fsigm(gf)*cp + fsigm(gi)*ftanh(gg);
  float hn = fsigm(go)*ftanh(cn);
  X[((size_t)(b*TD + (TD-1)))*1024 + e] = __float2bfloat16(hn);
  out[OUT_H + idx]               = h0buf[idx];  // h[0]
  out[OUT_H + NB*HD + idx]       = hn;          // h[1]
  out[OUT_C + idx]               = c0[idx];     // c[0]
  out[OUT_C + NB*HD + idx]       = cn;          // c[1]
}

// Logits GEMM: out[m][n] = sum_k X[m][k]*W[n][k] + bout[n].  M=4096, N=32000, K=1024.
// bf16 MFMA 16x16x32, 128x128 tile, XOR-swizzled LDS (verified m89/m91 fragment layouts).
__global__ __launch_bounds__(256) void k_gemm(const unsigned short* __restrict__ X,
                                              const unsigned short* __restrict__ W,
                                              const float* __restrict__ bout, float* __restrict__ out){
  __shared__ unsigned short As[128][64];
  __shared__ unsigned short Bs[128][64];
  int tid = threadIdx.x;
  int bn = blockIdx.x, bm = blockIdx.y;
  int wave = tid>>6, lane = tid&63;
  int wm = wave&1, wn = wave>>1;
  int r16 = lane&15, quad = lane>>4;
  f32x4 acc[4][4];
  #pragma unroll
  for (int i=0;i<4;i++)
    #pragma unroll
    for (int j=0;j<4;j++){ f32x4 z = {0.f,0.f,0.f,0.f}; acc[i][j] = z; }
  for (int k0=0;k0<1024;k0+=64){
    __syncthreads();
    #pragma unroll
    for (int i=0;i<4;i++){
      int idx = tid + i*256;
      int row = idx>>3, ch = idx&7;
      int sw = ch ^ (row&7);
      *(uint4*)&As[row][sw*8] = *(const uint4*)(X + (size_t)(bm*128+row)*1024 + k0 + ch*8);
      *(uint4*)&Bs[row][sw*8] = *(const uint4*)(W + (size_t)(bn*128+row)*1024 + k0 + ch*8);
    }
    __syncthreads();
    #pragma unroll
    for (int kk=0;kk<2;kk++){
      bf16x8 af[4], bf[4];
      #pragma unroll
      for (int i=0;i<4;i++){
        int ar = wm*64 + i*16 + r16;
        int ach = (kk*4 + quad) ^ (ar&7);
        af[i] = *(bf16x8*)&As[ar][ach*8];
        int br = wn*64 + i*16 + r16;
        int bch = (kk*4 + quad) ^ (br&7);
        bf[i] = *(bf16x8*)&Bs[br][bch*8];
      }
      #pragma unroll
      for (int i=0;i<4;i++)
        #pragma unroll
        for (int j=0;j<4;j++)
          acc[i][j] = __builtin_amdgcn_mfma_f32_16x16x32_bf16(af[i], bf[j], acc[i][j], 0,0,0);
    }
  }
  #pragma unroll
  for (int j=0;j<4;j++){
    int col = bn*128 + wn*64 + j*16 + r16;
    float bo = bout[col];
    #pragma unroll
    for (int i=0;i<4;i++){
      int row0 = bm*128 + wm*64 + i*16 + quad*4;
      #pragma unroll
      for (int r=0;r<4;r++)
        out[(size_t)(row0+r)*NV + col] = acc[i][j][r] + bo;
    }
  }
}

// ---------------- launch ----------------

extern "C" void kernel_launch(void* const* d_in, const int* in_sizes, int n_in,
                              void* d_out, int out_size, void* d_ws, size_t ws_size,
                              hipStream_t stream){
  (void)in_sizes; (void)n_in; (void)out_size; (void)ws_size;
  const float* enc  = (const float*)d_in[0];
  const int*   tok  = (const int*)d_in[1];
  const float* emb  = (const float*)d_in[2];
  const float* Wq   = (const float*)d_in[3];
  const float* bq   = (const float*)d_in[4];
  const float* Wk   = (const float*)d_in[5];
  const float* bk   = (const float*)d_in[6];
  const float* vv   = (const float*)d_in[7];
  const float* Wih0 = (const float*)d_in[8];
  const float* Whh0 = (const float*)d_in[9];
  const float* bih0 = (const float*)d_in[10];
  const float* bhh0 = (const float*)d_in[11];
  const float* Wih1 = (const float*)d_in[12];
  const float* Whh1 = (const float*)d_in[13];
  const float* bih1 = (const float*)d_in[14];
  const float* bhh1 = (const float*)d_in[15];
  const float* Wout = (const float*)d_in[16];
  const float* bout = (const float*)d_in[17];
  float* out = (float*)d_out;

  float* wsf = (float*)d_ws;
  // float-region offsets
  float* kp    = wsf + 0;            // 4,194,304
  float* emb_g = wsf + 4194304;      // 1,048,576
  float* qw    = wsf + 5242880;      // 16,384
  float* scores= wsf + 5259264;      // 8,192
  float* ctx   = wsf + 5267456;      // 16,384
  float* h1buf = wsf + 5283840;      // 16,384
  float* c1b   = wsf + 5300224;      // 16,384
  float* h0buf = wsf + 5316608;      // 16,384  <- zero region start
  float* c0    = wsf + 5332992;      // 16,384
  float* c1a   = wsf + 5349376;      // 16,384
  float* part1 = wsf + 5365760;      // 524,288 <- zero region end (573,440 total)
  float* part0 = wsf + 5890048;      // 524,288
  float* Wcat0 = wsf + 6414336;      // 2,621,440
  float* Wcat1 = wsf + 9035776;      // 2,097,152
  float* bcat0 = wsf + 11132928;     // 2,048
  float* bcat1 = wsf + 11134976;     // 2,048
  // bf16 region (byte offsets from base)
  char* wsb = (char*)d_ws;
  __hip_bfloat16* X = (__hip_bfloat16*)(wsb + 44548096);        // 4096*1024 bf16
  unsigned short* Woutb = (unsigned short*)(wsb + 52936704);    // 32000*1024 bf16

  // prologue
  hipLaunchKernelGGL(k_init,   dim3(2240), dim3(256), 0, stream, h0buf);
  hipLaunchKernelGGL(k_gather, dim3(NB*TD), dim3(256), 0, stream, emb, tok, emb_g);
  hipLaunchKernelGGL(k_keyproj,dim3(4,64), dim3(256), 0, stream, enc, Wk, bk, kp);
  hipLaunchKernelGGL(k_wcat0,  dim3(2048), dim3(256), 0, stream, Wih0, Whh0, bih0, bhh0, Wcat0, bcat0);
  hipLaunchKernelGGL(k_wcat1,  dim3(2048), dim3(256), 0, stream, Wih1, Whh1, bih1, bhh1, Wcat1, bcat1);
  hipLaunchKernelGGL(k_cvtw,   dim3(NV),   dim3(256), 0, stream, Wout, Woutb);

  for (int t=0; t<TD; t++){
    float* c1in  = (t&1) ? c1b : c1a;
    float* c1out = (t&1) ? c1a : c1b;
    hipLaunchKernelGGL(k_qw,     dim3(2,8),  dim3(256), 0, stream,
                       part1, bcat1, c1in, c1out, Wq, bq, qw, h1buf, X, t);
    hipLaunchKernelGGL(k_scores, dim3(8,NB), dim3(256), 0, stream, kp, qw, vv, scores);
    hipLaunchKernelGGL(k_ctx,    dim3(2,NB), dim3(256), 0, stream, scores, enc, ctx, X, t);
    hipLaunchKernelGGL(k_g0,     dim3(8,8),  dim3(256), 0, stream, Wcat0, emb_g, ctx, h0buf, part0, t);
    hipLaunchKernelGGL(k_g1,     dim3(8,8),  dim3(256), 0, stream, Wcat1, part0, bcat0, c0, h0buf, h1buf, part1);
  }
  // t=128 parity: c1in = c1a (written at t=127)
  hipLaunchKernelGGL(k_fin,  dim3(64), dim3(256), 0, stream, part1, bcat1, c1a, h0buf, c0, X, out);
  hipLaunchKernelGGL(k_gemm, dim3(NV/128, (NB*TD)/128), dim3(256), 0, stream,
                     (const unsigned short*)X, Woutb, bout, out);
}